// Round 1
// baseline (808.263 us; speedup 1.0000x reference)
//
#include <hip/hip_runtime.h>

// Problem constants (fixed by the reference)
#define NN 50000
#define EE 1600000
#define FIN 512
#define HH 128

// ---------------- setup kernels ----------------

__global__ void init_deg_kernel(float* __restrict__ deg, int n) {
    int i = blockIdx.x * 256 + threadIdx.x;
    if (i < n) deg[i] = 1.0f;  // self-loop weight
}

__global__ void count_kernel(const int* __restrict__ src, const int* __restrict__ dst,
                             const float* __restrict__ w,
                             float* __restrict__ deg, int* __restrict__ cnt, int e_total) {
    int e = blockIdx.x * 256 + threadIdx.x;
    if (e < e_total) {
        int d = dst[e];
        atomicAdd(deg + d, w[e]);
        atomicAdd(cnt + d, 1);
    }
}

__global__ void dinv_kernel(const float* __restrict__ deg, float* __restrict__ dinv, int n) {
    int i = blockIdx.x * 256 + threadIdx.x;
    if (i < n) {
        float d = deg[i];
        dinv[i] = (d > 0.0f) ? rsqrtf(d) : 0.0f;
    }
}

// single-block exclusive scan over n counts -> row_ptr[0..n]
__global__ __launch_bounds__(1024) void scan_kernel(const int* __restrict__ cnt,
                                                    int* __restrict__ row_ptr, int n) {
    __shared__ int buf[1024];
    __shared__ int carry_s;
    if (threadIdx.x == 0) carry_s = 0;
    __syncthreads();
    for (int base = 0; base < n; base += 1024) {
        int i = base + (int)threadIdx.x;
        int v = (i < n) ? cnt[i] : 0;
        buf[threadIdx.x] = v;
        __syncthreads();
        for (int off = 1; off < 1024; off <<= 1) {
            int t = (threadIdx.x >= (unsigned)off) ? buf[threadIdx.x - off] : 0;
            __syncthreads();
            buf[threadIdx.x] += t;
            __syncthreads();
        }
        int carry = carry_s;
        if (i < n) row_ptr[i] = carry + buf[threadIdx.x] - v;
        __syncthreads();
        if (threadIdx.x == 1023) carry_s = carry + buf[1023];
        __syncthreads();
    }
    if (threadIdx.x == 0) row_ptr[n] = carry_s;
}

__global__ void scatter_kernel(const int* __restrict__ src, const int* __restrict__ dst,
                               const float* __restrict__ w, const float* __restrict__ dinv,
                               const int* __restrict__ row_ptr, int* __restrict__ cursor,
                               int* __restrict__ csr_src, float* __restrict__ csr_norm,
                               int e_total) {
    int e = blockIdx.x * 256 + threadIdx.x;
    if (e < e_total) {
        int s = src[e], d = dst[e];
        int pos = row_ptr[d] + atomicAdd(cursor + d, 1);
        csr_src[pos] = s;
        csr_norm[pos] = dinv[s] * w[e] * dinv[d];
    }
}

// ---------------- GEMM: C[M,N] = A[M,K] * B[K,N] (+bias) ----------------
// BM=64, BN=128, BK=16; 256 threads; each thread computes 4x8.

#define BM 64
#define BN 128
#define BK 16

__global__ __launch_bounds__(256) void gemm_kernel(const float* __restrict__ A,
                                                   const float* __restrict__ B,
                                                   const float* __restrict__ bias,
                                                   float* __restrict__ C,
                                                   int M, int N, int K) {
    __shared__ float As[BM][BK + 1];
    __shared__ float Bs[BK][BN];
    const int bm = blockIdx.x * BM;
    const int bn = blockIdx.y * BN;
    const int tid = threadIdx.x;
    const int ty = tid >> 4;   // 0..15
    const int tx = tid & 15;   // 0..15

    float acc[4][8];
#pragma unroll
    for (int i = 0; i < 4; ++i)
#pragma unroll
        for (int j = 0; j < 8; ++j) acc[i][j] = 0.0f;

    const int a_row = tid >> 2;        // 0..63
    const int a_k   = (tid & 3) * 4;   // 0,4,8,12

    for (int k0 = 0; k0 < K; k0 += BK) {
        // A tile: 64x16, one float4 per thread
        {
            int gr = bm + a_row;
            float4 v = make_float4(0.f, 0.f, 0.f, 0.f);
            if (gr < M) v = *(const float4*)(A + (size_t)gr * K + k0 + a_k);
            As[a_row][a_k + 0] = v.x;
            As[a_row][a_k + 1] = v.y;
            As[a_row][a_k + 2] = v.z;
            As[a_row][a_k + 3] = v.w;
        }
        // B tile: 16x128, two float4 per thread
#pragma unroll
        for (int i = 0; i < 2; ++i) {
            int f = tid + i * 256;          // 0..511
            int kr = f >> 5;                // 0..15
            int col = (f & 31) * 4;         // 0..124
            float4 v = *(const float4*)(B + (size_t)(k0 + kr) * N + bn + col);
            *(float4*)&Bs[kr][col] = v;
        }
        __syncthreads();
#pragma unroll
        for (int kk = 0; kk < BK; ++kk) {
            float a_frag[4], b_frag[8];
#pragma unroll
            for (int i = 0; i < 4; ++i) a_frag[i] = As[ty * 4 + i][kk];
#pragma unroll
            for (int j = 0; j < 8; ++j) b_frag[j] = Bs[kk][tx * 8 + j];
#pragma unroll
            for (int i = 0; i < 4; ++i)
#pragma unroll
                for (int j = 0; j < 8; ++j) acc[i][j] += a_frag[i] * b_frag[j];
        }
        __syncthreads();
    }

#pragma unroll
    for (int i = 0; i < 4; ++i) {
        int gr = bm + ty * 4 + i;
        if (gr < M) {
#pragma unroll
            for (int j = 0; j < 8; j += 4) {
                int gc = bn + tx * 8 + j;
                float4 v;
                v.x = acc[i][j + 0];
                v.y = acc[i][j + 1];
                v.z = acc[i][j + 2];
                v.w = acc[i][j + 3];
                if (bias != nullptr) {
                    v.x += bias[gc + 0];
                    v.y += bias[gc + 1];
                    v.z += bias[gc + 2];
                    v.w += bias[gc + 3];
                }
                *(float4*)(C + (size_t)gr * N + gc) = v;
            }
        }
    }
}

// ---------------- aggregation: agg[n] = b_conv + dinv[n]^2*h[n] + sum_edges ----------------
// one block (128 threads) per dst node; thread t = feature t

__global__ __launch_bounds__(128) void agg_kernel(const float* __restrict__ h,
                                                  const int* __restrict__ row_ptr,
                                                  const int* __restrict__ csr_src,
                                                  const float* __restrict__ csr_norm,
                                                  const float* __restrict__ dinv,
                                                  const float* __restrict__ b_conv,
                                                  float* __restrict__ agg) {
    const int node = blockIdx.x;
    const int t = threadIdx.x;
    const float di = dinv[node];
    float acc = b_conv[t] + di * di * h[(size_t)node * HH + t];
    const int s = row_ptr[node];
    const int e2 = row_ptr[node + 1];
    int j = s;
    // unroll by 2 for a bit of MLP
    for (; j + 1 < e2; j += 2) {
        int s0 = csr_src[j];
        int s1 = csr_src[j + 1];
        float n0 = csr_norm[j];
        float n1 = csr_norm[j + 1];
        float v0 = h[(size_t)s0 * HH + t];
        float v1 = h[(size_t)s1 * HH + t];
        acc += n0 * v0 + n1 * v1;
    }
    if (j < e2) {
        int s0 = csr_src[j];
        acc += csr_norm[j] * h[(size_t)s0 * HH + t];
    }
    agg[(size_t)node * HH + t] = acc;
}

// ---------------- launch ----------------

extern "C" void kernel_launch(void* const* d_in, const int* in_sizes, int n_in,
                              void* d_out, int out_size, void* d_ws, size_t ws_size,
                              hipStream_t stream) {
    const float* x      = (const float*)d_in[0];
    const int*   ei     = (const int*)d_in[1];
    const float* ew     = (const float*)d_in[2];
    const float* W_conv = (const float*)d_in[3];
    const float* b_conv = (const float*)d_in[4];
    const float* W_lin  = (const float*)d_in[5];
    const float* b_lin  = (const float*)d_in[6];
    float* out = (float*)d_out;

    const int* src = ei;
    const int* dst = ei + EE;

    // workspace layout (bytes, 256-aligned chunks)
    char* ws = (char*)d_ws;
    float* deg      = (float*)(ws + 0);          // 200704
    float* dinv     = (float*)(ws + 200704);     // 200704
    int*   cnt      = (int*)  (ws + 401408);     // 200704
    int*   cursor   = (int*)  (ws + 602112);     // 200704
    int*   row_ptr  = (int*)  (ws + 802816);     // 200704 (N+1 ints)
    int*   csr_src  = (int*)  (ws + 1003520);    // 6400000
    float* csr_norm = (float*)(ws + 7403520);    // 6400000
    float* h        = (float*)(ws + 13803520);   // 25600000
    float* agg      = (float*)(ws + 39403520);   // 25600000
    // total: 65003520 bytes

    hipMemsetAsync(cnt, 0, NN * sizeof(int), stream);
    hipMemsetAsync(cursor, 0, NN * sizeof(int), stream);

    const int nb_n = (NN + 255) / 256;
    const int nb_e = (EE + 255) / 256;

    init_deg_kernel<<<nb_n, 256, 0, stream>>>(deg, NN);
    count_kernel<<<nb_e, 256, 0, stream>>>(src, dst, ew, deg, cnt, EE);
    dinv_kernel<<<nb_n, 256, 0, stream>>>(deg, dinv, NN);
    scan_kernel<<<1, 1024, 0, stream>>>(cnt, row_ptr, NN);
    scatter_kernel<<<nb_e, 256, 0, stream>>>(src, dst, ew, dinv, row_ptr, cursor,
                                             csr_src, csr_norm, EE);

    // GEMM1: h = x @ W_conv   (M=50000, N=128, K=512), no bias (b_conv folded into agg)
    {
        dim3 grid((NN + BM - 1) / BM, HH / BN);
        gemm_kernel<<<grid, 256, 0, stream>>>(x, W_conv, nullptr, h, NN, HH, FIN);
    }

    // aggregation
    agg_kernel<<<NN, HH, 0, stream>>>(h, row_ptr, csr_src, csr_norm, dinv, b_conv, agg);

    // GEMM2: out = agg @ W_lin + b_lin   (M=50000, N=512, K=128)
    {
        dim3 grid((NN + BM - 1) / BM, FIN / BN);
        gemm_kernel<<<grid, 256, 0, stream>>>(agg, W_lin, b_lin, out, NN, FIN, HH);
    }
}

// Round 2
// 621.474 us; speedup vs baseline: 1.3006x; 1.3006x over previous
//
#include <hip/hip_runtime.h>

// Problem constants (fixed by the reference)
#define NN 50000
#define EE 1600000
#define FIN 512
#define HH 128

#define CAP 80          // bucket capacity per dst node (Poisson(32); P(deg>80) ~ 1e-11)
#define OVF_CAP 65536   // overflow list capacity (never used in practice; correctness net)

// ---------------- build kernels ----------------

// Single-pass bucket scatter: 1 atomic + 1 packed 8B store per edge.
__global__ void bucket_scatter(const int* __restrict__ src, const int* __restrict__ dst,
                               const float* __restrict__ w,
                               int* __restrict__ cnt, int2* __restrict__ bucket,
                               int* __restrict__ ovf_cnt, int4* __restrict__ ovf, int e_total) {
    int e = blockIdx.x * 256 + threadIdx.x;
    if (e < e_total) {
        int s = src[e], d = dst[e];
        float we = w[e];
        int pos = atomicAdd(cnt + d, 1);
        if (pos < CAP) {
            bucket[d * CAP + pos] = make_int2(s, __float_as_int(we));
        } else {
            int o = atomicAdd(ovf_cnt, 1);
            if (o < OVF_CAP) ovf[o] = make_int4(s, d, __float_as_int(we), 0);
        }
    }
}

// Fallback path: count -> scan -> tight CSR scatter
__global__ void count_kernel(const int* __restrict__ dst, int* __restrict__ cnt, int e_total) {
    int e = blockIdx.x * 256 + threadIdx.x;
    if (e < e_total) atomicAdd(cnt + dst[e], 1);
}

__global__ __launch_bounds__(1024) void scan_kernel(const int* __restrict__ cnt,
                                                    int* __restrict__ row_ptr, int n) {
    __shared__ int buf[1024];
    __shared__ int carry_s;
    if (threadIdx.x == 0) carry_s = 0;
    __syncthreads();
    for (int base = 0; base < n; base += 1024) {
        int i = base + (int)threadIdx.x;
        int v = (i < n) ? cnt[i] : 0;
        buf[threadIdx.x] = v;
        __syncthreads();
        for (int off = 1; off < 1024; off <<= 1) {
            int t = (threadIdx.x >= (unsigned)off) ? buf[threadIdx.x - off] : 0;
            __syncthreads();
            buf[threadIdx.x] += t;
            __syncthreads();
        }
        int carry = carry_s;
        if (i < n) row_ptr[i] = carry + buf[threadIdx.x] - v;
        __syncthreads();
        if (threadIdx.x == 1023) carry_s = carry + buf[1023];
        __syncthreads();
    }
    if (threadIdx.x == 0) row_ptr[n] = carry_s;
}

__global__ void scatter_csr(const int* __restrict__ src, const int* __restrict__ dst,
                            const float* __restrict__ w, const int* __restrict__ row_ptr,
                            int* __restrict__ cursor, int2* __restrict__ csr, int e_total) {
    int e = blockIdx.x * 256 + threadIdx.x;
    if (e < e_total) {
        int d = dst[e];
        int pos = row_ptr[d] + atomicAdd(cursor + d, 1);
        csr[pos] = make_int2(src[e], __float_as_int(w[e]));
    }
}

// deg[node] = 1 + sum of edge weights into node. One 64-lane wave per node.
// mode=1: padded buckets (meta=cnt); mode=0: CSR (meta=row_ptr)
__global__ __launch_bounds__(256) void deg_kernel(const int* __restrict__ meta,
                                                  const int2* __restrict__ entries,
                                                  float* __restrict__ deg, int n, int mode) {
    int idx = blockIdx.x * 256 + threadIdx.x;
    int node = idx >> 6;
    int lane = idx & 63;
    if (node >= n) return;
    int start, c;
    if (mode) { start = node * CAP; c = min(meta[node], CAP); }
    else      { start = meta[node]; c = meta[node + 1] - start; }
    float s = 0.0f;
    for (int j = lane; j < c; j += 64) s += __int_as_float(entries[start + j].y);
#pragma unroll
    for (int off = 32; off > 0; off >>= 1) s += __shfl_down(s, off, 64);
    if (lane == 0) deg[node] = 1.0f + s;
}

__global__ void ovf_deg(const int* __restrict__ ovf_cnt, const int4* __restrict__ ovf,
                        float* __restrict__ deg) {
    int n = min(*ovf_cnt, OVF_CAP);
    for (int i = blockIdx.x * blockDim.x + threadIdx.x; i < n; i += blockDim.x * gridDim.x)
        atomicAdd(deg + ovf[i].y, __int_as_float(ovf[i].z));
}

__global__ void dinv_kernel(const float* __restrict__ deg, float* __restrict__ dinv, int n) {
    int i = blockIdx.x * 256 + threadIdx.x;
    if (i < n) {
        float d = deg[i];
        dinv[i] = (d > 0.0f) ? rsqrtf(d) : 0.0f;
    }
}

// ---------------- GEMM: C[M,N] = rowscale(A[M,K] * B[K,N]) + bias ----------------
// BM=64, BN=128, BK=16; 256 threads; each thread computes 4x8.

#define BM 64
#define BN 128
#define BK 16

__global__ __launch_bounds__(256) void gemm_kernel(const float* __restrict__ A,
                                                   const float* __restrict__ B,
                                                   const float* __restrict__ bias,
                                                   const float* __restrict__ row_scale,
                                                   float* __restrict__ C,
                                                   int M, int N, int K) {
    __shared__ float As[BM][BK + 1];
    __shared__ float Bs[BK][BN];
    const int bm = blockIdx.x * BM;
    const int bn = blockIdx.y * BN;
    const int tid = threadIdx.x;
    const int ty = tid >> 4;   // 0..15
    const int tx = tid & 15;   // 0..15

    float acc[4][8];
#pragma unroll
    for (int i = 0; i < 4; ++i)
#pragma unroll
        for (int j = 0; j < 8; ++j) acc[i][j] = 0.0f;

    const int a_row = tid >> 2;        // 0..63
    const int a_k   = (tid & 3) * 4;   // 0,4,8,12

    for (int k0 = 0; k0 < K; k0 += BK) {
        {
            int gr = bm + a_row;
            float4 v = make_float4(0.f, 0.f, 0.f, 0.f);
            if (gr < M) v = *(const float4*)(A + (size_t)gr * K + k0 + a_k);
            As[a_row][a_k + 0] = v.x;
            As[a_row][a_k + 1] = v.y;
            As[a_row][a_k + 2] = v.z;
            As[a_row][a_k + 3] = v.w;
        }
#pragma unroll
        for (int i = 0; i < 2; ++i) {
            int f = tid + i * 256;          // 0..511
            int kr = f >> 5;                // 0..15
            int col = (f & 31) * 4;         // 0..124
            float4 v = *(const float4*)(B + (size_t)(k0 + kr) * N + bn + col);
            *(float4*)&Bs[kr][col] = v;
        }
        __syncthreads();
#pragma unroll
        for (int kk = 0; kk < BK; ++kk) {
            float a_frag[4], b_frag[8];
#pragma unroll
            for (int i = 0; i < 4; ++i) a_frag[i] = As[ty * 4 + i][kk];
#pragma unroll
            for (int j = 0; j < 8; ++j) b_frag[j] = Bs[kk][tx * 8 + j];
#pragma unroll
            for (int i = 0; i < 4; ++i)
#pragma unroll
                for (int j = 0; j < 8; ++j) acc[i][j] += a_frag[i] * b_frag[j];
        }
        __syncthreads();
    }

#pragma unroll
    for (int i = 0; i < 4; ++i) {
        int gr = bm + ty * 4 + i;
        if (gr < M) {
            float sc = (row_scale != nullptr) ? row_scale[gr] : 1.0f;
#pragma unroll
            for (int j = 0; j < 8; j += 4) {
                int gc = bn + tx * 8 + j;
                float4 v;
                v.x = acc[i][j + 0] * sc;
                v.y = acc[i][j + 1] * sc;
                v.z = acc[i][j + 2] * sc;
                v.w = acc[i][j + 3] * sc;
                if (bias != nullptr) {
                    v.x += bias[gc + 0];
                    v.y += bias[gc + 1];
                    v.z += bias[gc + 2];
                    v.w += bias[gc + 3];
                }
                *(float4*)(C + (size_t)gr * N + gc) = v;
            }
        }
    }
}

// ---------------- aggregation ----------------
// h2 = dinv .* (x @ W_conv) already computed.
// agg[d] = b_conv + dinv[d] * (h2[d] + sum_e w_e * h2[src_e])
// one block (128 threads) per dst node; thread t = feature t

__global__ __launch_bounds__(128) void agg_kernel(const float* __restrict__ h2,
                                                  const int* __restrict__ meta,
                                                  const int2* __restrict__ entries,
                                                  const float* __restrict__ dinv,
                                                  const float* __restrict__ b_conv,
                                                  float* __restrict__ agg, int mode) {
    const int node = blockIdx.x;
    const int t = threadIdx.x;
    int start, c;
    if (mode) { start = node * CAP; c = min(meta[node], CAP); }
    else      { start = meta[node]; c = meta[node + 1] - start; }
    const float di = dinv[node];
    float acc = h2[(size_t)node * HH + t];
    const int2* e = entries + start;
    int j = 0;
    for (; j + 1 < c; j += 2) {
        int2 e0 = e[j];
        int2 e1 = e[j + 1];
        float v0 = h2[(size_t)e0.x * HH + t];
        float v1 = h2[(size_t)e1.x * HH + t];
        acc += __int_as_float(e0.y) * v0 + __int_as_float(e1.y) * v1;
    }
    if (j < c) {
        int2 e0 = e[j];
        acc += __int_as_float(e0.y) * h2[(size_t)e0.x * HH + t];
    }
    agg[(size_t)node * HH + t] = b_conv[t] + di * acc;
}

__global__ void ovf_agg(const int* __restrict__ ovf_cnt, const int4* __restrict__ ovf,
                        const float* __restrict__ h2, const float* __restrict__ dinv,
                        float* __restrict__ agg) {
    int n = min(*ovf_cnt, OVF_CAP) * HH;
    for (int i = blockIdx.x * blockDim.x + threadIdx.x; i < n; i += blockDim.x * gridDim.x) {
        int e = i >> 7, t = i & (HH - 1);
        int4 v = ovf[e];
        float contrib = dinv[v.y] * __int_as_float(v.z) * h2[(size_t)v.x * HH + t];
        atomicAdd(agg + (size_t)v.y * HH + t, contrib);
    }
}

// ---------------- launch ----------------

extern "C" void kernel_launch(void* const* d_in, const int* in_sizes, int n_in,
                              void* d_out, int out_size, void* d_ws, size_t ws_size,
                              hipStream_t stream) {
    const float* x      = (const float*)d_in[0];
    const int*   ei     = (const int*)d_in[1];
    const float* ew     = (const float*)d_in[2];
    const float* W_conv = (const float*)d_in[3];
    const float* b_conv = (const float*)d_in[4];
    const float* W_lin  = (const float*)d_in[5];
    const float* b_lin  = (const float*)d_in[6];
    float* out = (float*)d_out;

    const int* src = ei;
    const int* dst = ei + EE;

    const int nb_e = (EE + 255) / 256;
    const int nb_n = (NN + 255) / 256;
    const int nb_deg = (NN * 64 + 255) / 256;

    // ---- bucket-path workspace layout ----
    //   cnt      : 200704
    //   deg      : 200704
    //   dinv     : 200704
    //   ovf_cnt  : 256
    //   ovf      : OVF_CAP*16 = 1048576
    //   bucket   : NN*CAP*8   = 32000000
    //   h2       : NN*HH*4    = 25600000
    //   agg      : NN*HH*4    = 25600000
    const size_t BUCKET_NEED = 200704ull * 3 + 256 + (size_t)OVF_CAP * 16
                             + (size_t)NN * CAP * 8 + 25600000ull * 2;

    char* ws = (char*)d_ws;

    if (ws_size >= BUCKET_NEED) {
        // ---------- single-pass bucket path ----------
        int*   cnt     = (int*)  (ws + 0);
        float* deg     = (float*)(ws + 200704);
        float* dinv    = (float*)(ws + 401408);
        int*   ovf_cnt = (int*)  (ws + 602112);
        int4*  ovf     = (int4*) (ws + 602368);
        int2*  bucket  = (int2*) (ws + 1650944);
        float* h2      = (float*)(ws + 33650944);
        float* agg     = (float*)(ws + 59250944);

        hipMemsetAsync(cnt, 0, NN * sizeof(int), stream);
        hipMemsetAsync(ovf_cnt, 0, sizeof(int), stream);

        bucket_scatter<<<nb_e, 256, 0, stream>>>(src, dst, ew, cnt, bucket, ovf_cnt, ovf, EE);
        deg_kernel<<<nb_deg, 256, 0, stream>>>(cnt, bucket, deg, NN, 1);
        ovf_deg<<<4, 256, 0, stream>>>(ovf_cnt, ovf, deg);
        dinv_kernel<<<nb_n, 256, 0, stream>>>(deg, dinv, NN);

        // GEMM1: h2 = dinv .* (x @ W_conv)
        {
            dim3 grid((NN + BM - 1) / BM, HH / BN);
            gemm_kernel<<<grid, 256, 0, stream>>>(x, W_conv, nullptr, dinv, h2, NN, HH, FIN);
        }

        agg_kernel<<<NN, HH, 0, stream>>>(h2, cnt, bucket, dinv, b_conv, agg, 1);
        ovf_agg<<<8, 256, 0, stream>>>(ovf_cnt, ovf, h2, dinv, agg);

        // GEMM2: out = agg @ W_lin + b_lin
        {
            dim3 grid((NN + BM - 1) / BM, FIN / BN);
            gemm_kernel<<<grid, 256, 0, stream>>>(agg, W_lin, b_lin, nullptr, out, NN, FIN, HH);
        }
    } else {
        // ---------- tight-CSR fallback (fits in 65,003,520 bytes) ----------
        int*   cnt     = (int*)  (ws + 0);
        float* deg     = (float*)(ws + 200704);
        float* dinv    = (float*)(ws + 401408);
        int*   row_ptr = (int*)  (ws + 602112);   // N+1 ints
        int*   cursor  = (int*)  (ws + 802816);
        int2*  csr     = (int2*) (ws + 1003520);  // EE * 8 = 12800000
        float* h2      = (float*)(ws + 13803520);
        float* agg     = (float*)(ws + 39403520);

        hipMemsetAsync(cnt, 0, NN * sizeof(int), stream);
        hipMemsetAsync(cursor, 0, NN * sizeof(int), stream);

        count_kernel<<<nb_e, 256, 0, stream>>>(dst, cnt, EE);
        scan_kernel<<<1, 1024, 0, stream>>>(cnt, row_ptr, NN);
        scatter_csr<<<nb_e, 256, 0, stream>>>(src, dst, ew, row_ptr, cursor, csr, EE);
        deg_kernel<<<nb_deg, 256, 0, stream>>>(row_ptr, csr, deg, NN, 0);
        dinv_kernel<<<nb_n, 256, 0, stream>>>(deg, dinv, NN);

        {
            dim3 grid((NN + BM - 1) / BM, HH / BN);
            gemm_kernel<<<grid, 256, 0, stream>>>(x, W_conv, nullptr, dinv, h2, NN, HH, FIN);
        }

        agg_kernel<<<NN, HH, 0, stream>>>(h2, row_ptr, csr, dinv, b_conv, agg, 0);

        {
            dim3 grid((NN + BM - 1) / BM, FIN / BN);
            gemm_kernel<<<grid, 256, 0, stream>>>(agg, W_lin, b_lin, nullptr, out, NN, FIN, HH);
        }
    }
}

// Round 3
// 466.390 us; speedup vs baseline: 1.7330x; 1.3325x over previous
//
#include <hip/hip_runtime.h>

// Problem constants (fixed by the reference)
#define NN 50000
#define EE 1600000
#define FIN 512
#define HH 128

#define CAP 80          // bucket capacity per dst (Poisson(32); P(deg>80) ~ 1e-11)
#define OVF_CAP 65536   // overflow list capacity (correctness net, ~never used)

typedef short s16x8 __attribute__((ext_vector_type(8)));
typedef float f32x4 __attribute__((ext_vector_type(4)));

static __device__ inline unsigned short f2bf(float f) {
    // fp32 -> bf16 bits, round-to-nearest-even
    unsigned u = __float_as_uint(f);
    unsigned r = (u + 0x7fffu + ((u >> 16) & 1u)) >> 16;
    return (unsigned short)r;
}

// ---------------- build kernels ----------------

__global__ void bucket_scatter(const int* __restrict__ src, const int* __restrict__ dst,
                               const float* __restrict__ w,
                               int* __restrict__ cnt, int2* __restrict__ bucket,
                               int* __restrict__ ovf_cnt, int4* __restrict__ ovf, int e_total) {
    int e = blockIdx.x * 256 + threadIdx.x;
    if (e < e_total) {
        int s = src[e], d = dst[e];
        float we = w[e];
        int pos = atomicAdd(cnt + d, 1);
        if (pos < CAP) {
            bucket[d * CAP + pos] = make_int2(s, __float_as_int(we));
        } else {
            int o = atomicAdd(ovf_cnt, 1);
            if (o < OVF_CAP) ovf[o] = make_int4(s, d, __float_as_int(we), 0);
        }
    }
}

// deg[node] = 1 + sum of bucket weights. One 64-lane wave per node.
__global__ __launch_bounds__(256) void deg_kernel(const int* __restrict__ cnt,
                                                  const int2* __restrict__ bucket,
                                                  float* __restrict__ deg, int n) {
    int idx = blockIdx.x * 256 + threadIdx.x;
    int node = idx >> 6;
    int lane = idx & 63;
    if (node >= n) return;
    int c = min(cnt[node], CAP);
    const int2* e = bucket + node * CAP;
    float s = 0.0f;
    for (int j = lane; j < c; j += 64) s += __int_as_float(e[j].y);
#pragma unroll
    for (int off = 32; off > 0; off >>= 1) s += __shfl_down(s, off, 64);
    if (lane == 0) deg[node] = 1.0f + s;
}

__global__ void ovf_deg(const int* __restrict__ ovf_cnt, const int4* __restrict__ ovf,
                        float* __restrict__ deg) {
    int n = min(*ovf_cnt, OVF_CAP);
    for (int i = blockIdx.x * blockDim.x + threadIdx.x; i < n; i += blockDim.x * gridDim.x)
        atomicAdd(deg + ovf[i].y, __int_as_float(ovf[i].z));
}

__global__ void dinv_kernel(const float* __restrict__ deg, float* __restrict__ dinv, int n) {
    int i = blockIdx.x * 256 + threadIdx.x;
    if (i < n) {
        float d = deg[i];
        dinv[i] = (d > 0.0f) ? rsqrtf(d) : 0.0f;
    }
}

// ---------------- GEMM1: h2[M,128](bf16) = dinv .* (x[M,512](f32) @ Wc[512,128](f32)) ----
// 256 threads = 4 waves in 2x2; tile 128x128; BK=32; 16x16x32 bf16 MFMA, 4x4 frags/wave.

__global__ __launch_bounds__(256) void gemm1_kernel(const float* __restrict__ A,
                                                    const float* __restrict__ B,
                                                    const float* __restrict__ dinv,
                                                    unsigned short* __restrict__ h2,
                                                    int M) {
    __shared__ short As[128][40];   // [m][k], pad to 40 (80B rows)
    __shared__ short Bs[128][40];   // [n][k]
    const int bm = blockIdx.x * 128;
    const int tid = threadIdx.x;
    const int wave = tid >> 6, lane = tid & 63;
    const int wm = wave >> 1, wn = wave & 1;
    const int mlane = lane & 15, quad = lane >> 4;

    f32x4 acc[4][4];
#pragma unroll
    for (int i = 0; i < 4; ++i)
#pragma unroll
        for (int j = 0; j < 4; ++j) acc[i][j] = (f32x4){0.f, 0.f, 0.f, 0.f};

    for (int k0 = 0; k0 < FIN; k0 += 32) {
        // A tile: 128 rows x 32 k, fp32 -> bf16. 1024 float4 tasks, 4/thread.
#pragma unroll
        for (int i = 0; i < 4; ++i) {
            int task = tid + i * 256;
            int row = task >> 3, kq = task & 7;
            int grow = bm + row;
            float4 v = make_float4(0.f, 0.f, 0.f, 0.f);
            if (grow < M) v = *(const float4*)(A + (size_t)grow * FIN + k0 + kq * 4);
            ushort4 b;
            b.x = f2bf(v.x); b.y = f2bf(v.y); b.z = f2bf(v.z); b.w = f2bf(v.w);
            *(ushort4*)&As[row][kq * 4] = b;
        }
        // B tile: 32 k x 128 n, transposed to [n][k]. 512 tasks (n, kg), 2/thread.
#pragma unroll
        for (int i = 0; i < 2; ++i) {
            int task = tid + i * 256;
            int n = task & 127, kg = task >> 7;   // kg 0..3
            unsigned short tmp[8];
#pragma unroll
            for (int j = 0; j < 8; ++j)
                tmp[j] = f2bf(B[(size_t)(k0 + kg * 8 + j) * HH + n]);
            *(s16x8*)&Bs[n][kg * 8] = *(s16x8*)tmp;
        }
        __syncthreads();

        s16x8 af[4], bfr[4];
#pragma unroll
        for (int mt = 0; mt < 4; ++mt)
            af[mt] = *(const s16x8*)&As[wm * 64 + mt * 16 + mlane][quad * 8];
#pragma unroll
        for (int nt = 0; nt < 4; ++nt)
            bfr[nt] = *(const s16x8*)&Bs[wn * 64 + nt * 16 + mlane][quad * 8];
#pragma unroll
        for (int mt = 0; mt < 4; ++mt)
#pragma unroll
            for (int nt = 0; nt < 4; ++nt)
                acc[mt][nt] = __builtin_amdgcn_mfma_f32_16x16x32_bf16(af[mt], bfr[nt], acc[mt][nt], 0, 0, 0);
        __syncthreads();
    }

    // epilogue: D[row=quad*4+r][col=lane&15] per frag; scale by dinv, store bf16
#pragma unroll
    for (int mt = 0; mt < 4; ++mt) {
#pragma unroll
        for (int r = 0; r < 4; ++r) {
            int row = bm + wm * 64 + mt * 16 + quad * 4 + r;
            if (row < M) {
                float sc = dinv[row];
#pragma unroll
                for (int nt = 0; nt < 4; ++nt) {
                    int col = wn * 64 + nt * 16 + mlane;
                    h2[(size_t)row * HH + col] = f2bf(acc[mt][nt][r] * sc);
                }
            }
        }
    }
}

// ---------------- aggregation (bf16 in / bf16 out) ----------------
// agg[d] = bf16( b_conv + dinv[d] * (h2[d] + sum_e w_e * h2[src_e]) )
// one 64-lane wave per node; each lane owns feature pair (2*lane, 2*lane+1) as packed uint.

__global__ __launch_bounds__(256) void agg_kernel(const unsigned int* __restrict__ h2u,
                                                  const int* __restrict__ cnt,
                                                  const int2* __restrict__ bucket,
                                                  const float* __restrict__ dinv,
                                                  const float* __restrict__ b_conv,
                                                  const int* __restrict__ ovf_cnt,
                                                  const int4* __restrict__ ovf,
                                                  unsigned int* __restrict__ aggu, int n) {
    int idx = blockIdx.x * 256 + threadIdx.x;
    int node = idx >> 6;
    int lane = idx & 63;
    if (node >= n) return;
    int c = min(cnt[node], CAP);
    const int2* e = bucket + node * CAP;

    unsigned self = h2u[(size_t)node * 64 + lane];
    float acc0 = __uint_as_float(self << 16);
    float acc1 = __uint_as_float(self & 0xffff0000u);

    int j = 0;
    for (; j + 1 < c; j += 2) {
        int2 e0 = e[j], e1 = e[j + 1];
        float w0 = __int_as_float(e0.y), w1 = __int_as_float(e1.y);
        unsigned u0 = h2u[(size_t)e0.x * 64 + lane];
        unsigned u1 = h2u[(size_t)e1.x * 64 + lane];
        acc0 += w0 * __uint_as_float(u0 << 16) + w1 * __uint_as_float(u1 << 16);
        acc1 += w0 * __uint_as_float(u0 & 0xffff0000u) + w1 * __uint_as_float(u1 & 0xffff0000u);
    }
    if (j < c) {
        int2 e0 = e[j];
        float w0 = __int_as_float(e0.y);
        unsigned u0 = h2u[(size_t)e0.x * 64 + lane];
        acc0 += w0 * __uint_as_float(u0 << 16);
        acc1 += w0 * __uint_as_float(u0 & 0xffff0000u);
    }

    // overflow net (ovf_n is ~always 0)
    int ovf_n = min(*ovf_cnt, OVF_CAP);
    for (int i = 0; i < ovf_n; ++i) {
        int4 v = ovf[i];
        if (v.y == node) {
            float w0 = __int_as_float(v.z);
            unsigned u0 = h2u[(size_t)v.x * 64 + lane];
            acc0 += w0 * __uint_as_float(u0 << 16);
            acc1 += w0 * __uint_as_float(u0 & 0xffff0000u);
        }
    }

    float di = dinv[node];
    float2 bc = *(const float2*)&b_conv[lane * 2];
    float v0 = bc.x + di * acc0;
    float v1 = bc.y + di * acc1;
    aggu[(size_t)node * 64 + lane] = (unsigned)f2bf(v0) | ((unsigned)f2bf(v1) << 16);
}

// ---------------- GEMM2: out[M,512](f32) = agg[M,128](bf16) @ Wl[128,512](f32) + b_lin ----

__global__ __launch_bounds__(256) void gemm2_kernel(const unsigned short* __restrict__ A,
                                                    const float* __restrict__ B,
                                                    const float* __restrict__ bias,
                                                    float* __restrict__ C,
                                                    int M) {
    __shared__ short As[128][40];
    __shared__ short Bs[128][40];
    const int bm = blockIdx.x * 128;
    const int bn = blockIdx.y * 128;
    const int tid = threadIdx.x;
    const int wave = tid >> 6, lane = tid & 63;
    const int wm = wave >> 1, wn = wave & 1;
    const int mlane = lane & 15, quad = lane >> 4;

    f32x4 acc[4][4];
#pragma unroll
    for (int i = 0; i < 4; ++i)
#pragma unroll
        for (int j = 0; j < 4; ++j) acc[i][j] = (f32x4){0.f, 0.f, 0.f, 0.f};

    for (int k0 = 0; k0 < HH; k0 += 32) {
        // A tile: 128 rows x 32 k bf16, direct copy. 512 16B tasks, 2/thread.
#pragma unroll
        for (int i = 0; i < 2; ++i) {
            int task = tid + i * 256;
            int row = task >> 2, ch = task & 3;
            int grow = bm + row;
            s16x8 v = (s16x8){0, 0, 0, 0, 0, 0, 0, 0};
            if (grow < M) v = *(const s16x8*)(A + (size_t)grow * HH + k0 + ch * 8);
            *(s16x8*)&As[row][ch * 8] = v;
        }
        // B tile: 32 k x 128 n fp32 -> bf16, transposed to [n][k].
#pragma unroll
        for (int i = 0; i < 2; ++i) {
            int task = tid + i * 256;
            int n = task & 127, kg = task >> 7;
            unsigned short tmp[8];
#pragma unroll
            for (int j = 0; j < 8; ++j)
                tmp[j] = f2bf(B[(size_t)(k0 + kg * 8 + j) * FIN + bn + n]);
            *(s16x8*)&Bs[n][kg * 8] = *(s16x8*)tmp;
        }
        __syncthreads();

        s16x8 af[4], bfr[4];
#pragma unroll
        for (int mt = 0; mt < 4; ++mt)
            af[mt] = *(const s16x8*)&As[wm * 64 + mt * 16 + mlane][quad * 8];
#pragma unroll
        for (int nt = 0; nt < 4; ++nt)
            bfr[nt] = *(const s16x8*)&Bs[wn * 64 + nt * 16 + mlane][quad * 8];
#pragma unroll
        for (int mt = 0; mt < 4; ++mt)
#pragma unroll
            for (int nt = 0; nt < 4; ++nt)
                acc[mt][nt] = __builtin_amdgcn_mfma_f32_16x16x32_bf16(af[mt], bfr[nt], acc[mt][nt], 0, 0, 0);
        __syncthreads();
    }

#pragma unroll
    for (int mt = 0; mt < 4; ++mt) {
#pragma unroll
        for (int r = 0; r < 4; ++r) {
            int row = bm + wm * 64 + mt * 16 + quad * 4 + r;
            if (row < M) {
#pragma unroll
                for (int nt = 0; nt < 4; ++nt) {
                    int col = bn + wn * 64 + nt * 16 + mlane;
                    C[(size_t)row * FIN + col] = acc[mt][nt][r] + bias[col];
                }
            }
        }
    }
}

// ---------------- launch ----------------

extern "C" void kernel_launch(void* const* d_in, const int* in_sizes, int n_in,
                              void* d_out, int out_size, void* d_ws, size_t ws_size,
                              hipStream_t stream) {
    const float* x      = (const float*)d_in[0];
    const int*   ei     = (const int*)d_in[1];
    const float* ew     = (const float*)d_in[2];
    const float* W_conv = (const float*)d_in[3];
    const float* b_conv = (const float*)d_in[4];
    const float* W_lin  = (const float*)d_in[5];
    const float* b_lin  = (const float*)d_in[6];
    float* out = (float*)d_out;

    const int* src = ei;
    const int* dst = ei + EE;

    // workspace layout (bytes, 256-aligned):
    char* ws = (char*)d_ws;
    int*            cnt     = (int*)           (ws + 0);          //   200,704
    float*          deg     = (float*)         (ws + 200704);     //   200,704
    float*          dinv    = (float*)         (ws + 401408);     //   200,704
    int*            ovf_cnt = (int*)           (ws + 602112);     //       256
    int4*           ovf     = (int4*)          (ws + 602368);     // 1,048,576
    int2*           bucket  = (int2*)          (ws + 1650944);    // 32,000,000
    unsigned short* h2      = (unsigned short*)(ws + 33650944);   // 12,800,000
    unsigned short* agg     = (unsigned short*)(ws + 46450944);   // 12,800,000
    // end: 59,250,944 bytes

    hipMemsetAsync(cnt, 0, NN * sizeof(int), stream);
    hipMemsetAsync(ovf_cnt, 0, sizeof(int), stream);

    const int nb_e = (EE + 255) / 256;
    const int nb_n = (NN + 255) / 256;
    const int nb_w = (NN * 64 + 255) / 256;   // one wave per node

    bucket_scatter<<<nb_e, 256, 0, stream>>>(src, dst, ew, cnt, bucket, ovf_cnt, ovf, EE);
    deg_kernel<<<nb_w, 256, 0, stream>>>(cnt, bucket, deg, NN);
    ovf_deg<<<4, 256, 0, stream>>>(ovf_cnt, ovf, deg);
    dinv_kernel<<<nb_n, 256, 0, stream>>>(deg, dinv, NN);

    // GEMM1: h2 = bf16(dinv .* (x @ W_conv))
    gemm1_kernel<<<dim3((NN + 127) / 128, 1), 256, 0, stream>>>(x, W_conv, dinv, h2, NN);

    // aggregation (bf16 -> bf16)
    agg_kernel<<<nb_w, 256, 0, stream>>>((const unsigned int*)h2, cnt, bucket, dinv, b_conv,
                                         ovf_cnt, ovf, (unsigned int*)agg, NN);

    // GEMM2: out = agg @ W_lin + b_lin
    gemm2_kernel<<<dim3((NN + 127) / 128, FIN / 128), 256, 0, stream>>>(agg, W_lin, b_lin, out, NN);
}